// Round 1
// baseline (49.582 us; speedup 1.0000x reference)
//
#include <hip/hip_runtime.h>
#include <stdint.h>

#define B_   32
#define L_   8192
#define D_   128
#define KTOP 512

// ---------------- Threefry-2x32, key = (0, 42), 20 rounds ----------------
// jax.random.key(42) -> key pair (0, 42).
// threefry_partitionable=True (modern JAX default) 32-bit path:
//   counts = 64-bit flat iota -> (hi, lo); bits = x0 ^ x1 of block (hi, lo).
// For our size hi == 0, lo == p.
__device__ __forceinline__ uint32_t rotl32(uint32_t x, int d) {
    return (x << d) | (x >> (32 - d));
}

__device__ __forceinline__ uint32_t threefry_bits(uint32_t p) {
    const uint32_t k0 = 0u, k1 = 42u;
    const uint32_t k2 = 0x1BD11BDAu ^ k0 ^ k1;
    uint32_t x0 = 0u + k0;   // c0 + ks0
    uint32_t x1 = p + k1;    // c1 + ks1
#define TF_R(r) { x0 += x1; x1 = rotl32(x1, r); x1 ^= x0; }
    TF_R(13) TF_R(15) TF_R(26) TF_R(6)   x0 += k1; x1 += k2 + 1u;
    TF_R(17) TF_R(29) TF_R(16) TF_R(24)  x0 += k2; x1 += k0 + 2u;
    TF_R(13) TF_R(15) TF_R(26) TF_R(6)   x0 += k0; x1 += k1 + 3u;
    TF_R(17) TF_R(29) TF_R(16) TF_R(24)  x0 += k1; x1 += k2 + 4u;
    TF_R(13) TF_R(15) TF_R(26) TF_R(6)   x0 += k2; x1 += k0 + 5u;
#undef TF_R
    return x0 ^ x1;
}

// One block per batch row. Computes logits, exact radix-select of the 512th
// largest packed key, bitonic sort of the 512 winners, writes indices (as
// float) and a keep-bitmap for the scatter kernel.
__global__ __launch_bounds__(1024) void select_kernel(
        const float* __restrict__ probs, const float* __restrict__ mask,
        float* __restrict__ out_ind, uint32_t* __restrict__ keepw) {
    const int b   = blockIdx.x;
    const int tid = threadIdx.x;

    __shared__ uint32_t hist[256];
    __shared__ uint32_t scanbuf[256];
    __shared__ uint64_t sel[KTOP];
    __shared__ uint32_t s_cnt, s_bin, s_above;

    // zero this row's keep bitmap (256 words = 8192 bits)
    if (tid < 256) keepw[b * 256 + tid] = 0u;

    // ---- compute packed sort keys: (monotone(y) << 16) | (8191 - l) ----
    uint64_t K[8];
#pragma unroll
    for (int j = 0; j < 8; ++j) {
        const int l = j * 1024 + tid;
        const int p = b * L_ + l;
        const uint32_t bits = threefry_bits((uint32_t)p);
        const float U = __uint_as_float((bits >> 9) | 0x3F800000u) - 1.0f;
        const float g = -logf(-logf(U + 1e-20f) + 1e-20f);
        const float y = probs[p] / 0.1f + g + mask[p] * (-10000.0f);
        const uint32_t u = __float_as_uint(y);
        const uint32_t mono = u ^ ((u & 0x80000000u) ? 0xFFFFFFFFu : 0x80000000u);
        K[j] = ((uint64_t)mono << 16) | (uint32_t)(8191 - l);
    }

    // ---- 6-pass radix select: find exact value of 512th-largest key ----
    uint64_t prefix = 0;
    uint32_t needed = KTOP;
    for (int pass = 0; pass < 6; ++pass) {
        const int shift = 40 - pass * 8;
        if (tid < 256) hist[tid] = 0u;
        __syncthreads();
#pragma unroll
        for (int j = 0; j < 8; ++j) {
            if ((K[j] >> (shift + 8)) == prefix)
                atomicAdd(&hist[(uint32_t)(K[j] >> shift) & 255u], 1u);
        }
        __syncthreads();
        if (tid < 256) scanbuf[tid] = hist[tid];
        __syncthreads();
        // inclusive suffix scan: scanbuf[t] = sum_{i>=t} hist[i]
        for (int off = 1; off < 256; off <<= 1) {
            uint32_t v = 0;
            if (tid < 256) {
                v = scanbuf[tid];
                if (tid + off < 256) v += scanbuf[tid + off];
            }
            __syncthreads();
            if (tid < 256) scanbuf[tid] = v;
            __syncthreads();
        }
        if (tid < 256) {
            const uint32_t S  = scanbuf[tid];
            const uint32_t Sn = (tid == 255) ? 0u : scanbuf[tid + 1];
            if (S >= needed && Sn < needed) { s_bin = (uint32_t)tid; s_above = Sn; }
        }
        __syncthreads();
        prefix = (prefix << 8) | s_bin;
        needed -= s_above;
        __syncthreads();
    }
    const uint64_t Kthr = prefix;   // exact 512th-largest key (keys unique)

    if (tid == 0) s_cnt = 0u;
    __syncthreads();
#pragma unroll
    for (int j = 0; j < 8; ++j) {
        if (K[j] >= Kthr) {
            const uint32_t pos = atomicAdd(&s_cnt, 1u);
            if (pos < KTOP) sel[pos] = K[j];
        }
    }
    __syncthreads();

    // ---- bitonic sort, descending (value desc, index asc via packing) ----
    for (int size = 2; size <= KTOP; size <<= 1) {
        for (int stride = size >> 1; stride > 0; stride >>= 1) {
            __syncthreads();
            if (tid < KTOP) {
                const int partner = tid ^ stride;
                if (partner > tid) {
                    const uint64_t a = sel[tid], c = sel[partner];
                    const bool up = ((tid & size) == 0);
                    const bool sw = up ? (a < c) : (a > c);
                    if (sw) { sel[tid] = c; sel[partner] = a; }
                }
            }
        }
    }
    __syncthreads();

    if (tid < KTOP) {
        const uint32_t idx = 8191u - (uint32_t)(sel[tid] & 0xFFFFu);
        out_ind[b * KTOP + tid] = (float)idx;
        atomicOr(&keepw[b * 256 + (idx >> 5)], 1u << (idx & 31u));
    }
}

// Writes the full [B, L, D] output: reps row if kept, zeros otherwise.
// Only kept rows are read from HBM (~6.25% of reps).
__global__ __launch_bounds__(256) void scatter_kernel(
        const float* __restrict__ reps, const uint32_t* __restrict__ keepw,
        float* __restrict__ out) {
    const uint32_t i   = blockIdx.x * 256u + threadIdx.x;  // float4 index
    const uint32_t row = i >> 5;                           // 32 float4 per row
    const uint32_t w   = keepw[i >> 10];
    float4 v = make_float4(0.f, 0.f, 0.f, 0.f);
    if ((w >> (row & 31u)) & 1u) v = ((const float4*)reps)[i];
    ((float4*)out)[i] = v;
}

extern "C" void kernel_launch(void* const* d_in, const int* in_sizes, int n_in,
                              void* d_out, int out_size, void* d_ws, size_t ws_size,
                              hipStream_t stream) {
    const float* reps  = (const float*)d_in[0];
    const float* probs = (const float*)d_in[1];
    const float* mask  = (const float*)d_in[2];
    float* out     = (float*)d_out;
    float* out_ind = out + (size_t)B_ * L_ * D_;
    uint32_t* keepw = (uint32_t*)d_ws;   // B_*L_/32 = 8192 words (32 KB)

    hipLaunchKernelGGL(select_kernel, dim3(B_), dim3(1024), 0, stream,
                       probs, mask, out_ind, keepw);
    const int n4 = (B_ * L_ * D_) / 4;   // 8,388,608 float4 elements
    hipLaunchKernelGGL(scatter_kernel, dim3(n4 / 256), dim3(256), 0, stream,
                       reps, keepw, out);
}

// Round 2
// 46.080 us; speedup vs baseline: 1.0760x; 1.0760x over previous
//
#include <hip/hip_runtime.h>
#include <stdint.h>

#define B_   32
#define L_   8192
#define D_   128
#define KTOP 512
#define NBINS 4096
#define CAP  1024   // candidate capacity (sel[] size)

// ---------------- Threefry-2x32, key = (0, 42), 20 rounds ----------------
// jax.random.key(42) -> key pair (0, 42); threefry_partitionable 32-bit path:
// bits(p) = x0 ^ x1 of block (hi=0, lo=p).
__device__ __forceinline__ uint32_t rotl32(uint32_t x, int d) {
    return (x << d) | (x >> (32 - d));
}

__device__ __forceinline__ uint32_t threefry_bits(uint32_t p) {
    const uint32_t k0 = 0u, k1 = 42u;
    const uint32_t k2 = 0x1BD11BDAu ^ k0 ^ k1;
    uint32_t x0 = 0u + k0;   // c0 + ks0
    uint32_t x1 = p + k1;    // c1 + ks1
#define TF_R(r) { x0 += x1; x1 = rotl32(x1, r); x1 ^= x0; }
    TF_R(13) TF_R(15) TF_R(26) TF_R(6)   x0 += k1; x1 += k2 + 1u;
    TF_R(17) TF_R(29) TF_R(16) TF_R(24)  x0 += k2; x1 += k0 + 2u;
    TF_R(13) TF_R(15) TF_R(26) TF_R(6)   x0 += k0; x1 += k1 + 3u;
    TF_R(17) TF_R(29) TF_R(16) TF_R(24)  x0 += k1; x1 += k2 + 4u;
    TF_R(13) TF_R(15) TF_R(26) TF_R(6)   x0 += k2; x1 += k0 + 5u;
#undef TF_R
    return x0 ^ x1;
}

// One block per batch row. Computes packed keys, finds a conservative
// threshold via ONE 12-bit histogram (refine loop for pathological ties),
// compacts <=1024 candidates, rank-positions them (no sort), writes indices
// (as float) and a keep-bitmap for the scatter kernel.
__global__ __launch_bounds__(1024) void select_kernel(
        const float* __restrict__ probs, const float* __restrict__ mask,
        float* __restrict__ out_ind, uint32_t* __restrict__ keepw) {
    const int b    = blockIdx.x;
    const int tid  = threadIdx.x;
    const int lane = tid & 63;
    const int wid  = tid >> 6;

    __shared__ uint32_t hist[NBINS];       // 16 KB
    __shared__ uint64_t sel[CAP];          // 8 KB
    __shared__ uint32_t wtot[16];
    __shared__ uint32_t s_bin, s_above, s_candv, s_cnt;

    // zero this row's keep bitmap (256 words = 8192 bits)
    if (tid < 256) keepw[b * 256 + tid] = 0u;

    // ---- packed sort keys: (monotone(y) << 16) | (8191 - l) ----
    uint64_t K[8];
#pragma unroll
    for (int j = 0; j < 8; ++j) {
        const int l = j * 1024 + tid;
        const int p = b * L_ + l;
        const uint32_t bits = threefry_bits((uint32_t)p);
        const float U = __uint_as_float((bits >> 9) | 0x3F800000u) - 1.0f;
        const float g = -logf(-logf(U + 1e-20f) + 1e-20f);
        const float y = probs[p] / 0.1f + g + mask[p] * (-10000.0f);
        const uint32_t u = __float_as_uint(y);
        const uint32_t mono = u ^ ((u & 0x80000000u) ? 0xFFFFFFFFu : 0x80000000u);
        K[j] = ((uint64_t)mono << 16) | (uint32_t)(8191 - l);
    }

    // ---- threshold search: 12-bit digits, usually exits after level 0 ----
    uint64_t prefix = 0;
    uint32_t needed = KTOP;
    uint64_t thrlo  = 0;
    for (int level = 0; level < 4; ++level) {
        const int shift = 36 - level * 12;
        // zero histogram
        for (int i = tid; i < NBINS; i += 1024) hist[i] = 0u;
        __syncthreads();
#pragma unroll
        for (int j = 0; j < 8; ++j) {
            const bool match = (level == 0) || ((K[j] >> (shift + 12)) == prefix);
            if (match) atomicAdd(&hist[(uint32_t)(K[j] >> shift) & (NBINS - 1u)], 1u);
        }
        __syncthreads();

        // suffix scan: thread t owns bins 4t..4t+3
        const uint32_t h0 = hist[4 * tid + 0];
        const uint32_t h1 = hist[4 * tid + 1];
        const uint32_t h2 = hist[4 * tid + 2];
        const uint32_t h3 = hist[4 * tid + 3];
        const uint32_t ls = h0 + h1 + h2 + h3;
        // wave-level inclusive suffix scan
        uint32_t s = ls;
#pragma unroll
        for (int off = 1; off < 64; off <<= 1) {
            const uint32_t v = __shfl_down(s, off);
            if (lane + off < 64) s += v;
        }
        if (lane == 0) wtot[wid] = s;      // whole-wave sum
        __syncthreads();
        uint32_t after_waves = 0;
        for (int w = wid + 1; w < 16; ++w) after_waves += wtot[w];
        const uint32_t base = after_waves + (s - ls);  // sum of bins after my 4
        const uint32_t s3 = h3 + base;
        const uint32_t s2 = h2 + s3;
        const uint32_t s1 = h1 + s2;
        const uint32_t s0 = h0 + s1;
        if (s0 >= needed && s1 < needed)  { s_bin = 4u*tid+0u; s_above = s1;  s_candv = s0; }
        if (s1 >= needed && s2 < needed)  { s_bin = 4u*tid+1u; s_above = s2;  s_candv = s1; }
        if (s2 >= needed && s3 < needed)  { s_bin = 4u*tid+2u; s_above = s3;  s_candv = s2; }
        if (s3 >= needed && base < needed){ s_bin = 4u*tid+3u; s_above = base;s_candv = s3; }
        __syncthreads();

        const uint32_t T = s_bin;
        thrlo = ((prefix << 12) | T) << shift;          // conservative threshold
        const uint32_t G = s_candv + (KTOP - needed);   // global candidate count
        if (G <= CAP) break;                            // ~always at level 0
        prefix = (prefix << 12) | T;
        needed -= s_above;
        __syncthreads();
    }

    // ---- compact candidates (keys >= thrlo) ----
    if (tid == 0) s_cnt = 0u;
    __syncthreads();
#pragma unroll
    for (int j = 0; j < 8; ++j) {
        if (K[j] >= thrlo) {
            const uint32_t pos = atomicAdd(&s_cnt, 1u);
            sel[pos] = K[j];
        }
    }
    __syncthreads();
    const uint32_t nc = s_cnt;

    // ---- rank-position: r = #{candidates with larger key}; write r < KTOP ----
    if (tid < (int)nc) {
        const uint64_t mine = sel[tid];
        uint32_t r = 0;
        uint32_t i = 0;
        for (; i + 4 <= nc; i += 4) {
            r += (uint32_t)(sel[i]     > mine);
            r += (uint32_t)(sel[i + 1] > mine);
            r += (uint32_t)(sel[i + 2] > mine);
            r += (uint32_t)(sel[i + 3] > mine);
        }
        for (; i < nc; ++i) r += (uint32_t)(sel[i] > mine);
        if (r < KTOP) {
            const uint32_t idx = 8191u - (uint32_t)(mine & 0xFFFFu);
            out_ind[b * KTOP + r] = (float)idx;
            atomicOr(&keepw[b * 256 + (idx >> 5)], 1u << (idx & 31u));
        }
    }
}

// Writes the full [B, L, D] output: reps row if kept, zeros otherwise.
// Only kept rows are read from HBM (~6.25% of reps).
__global__ __launch_bounds__(256) void scatter_kernel(
        const float* __restrict__ reps, const uint32_t* __restrict__ keepw,
        float* __restrict__ out) {
    const uint32_t i   = blockIdx.x * 256u + threadIdx.x;  // float4 index
    const uint32_t row = i >> 5;                           // 32 float4 per row
    const uint32_t w   = keepw[i >> 10];
    float4 v = make_float4(0.f, 0.f, 0.f, 0.f);
    if ((w >> (row & 31u)) & 1u) v = ((const float4*)reps)[i];
    ((float4*)out)[i] = v;
}

extern "C" void kernel_launch(void* const* d_in, const int* in_sizes, int n_in,
                              void* d_out, int out_size, void* d_ws, size_t ws_size,
                              hipStream_t stream) {
    const float* reps  = (const float*)d_in[0];
    const float* probs = (const float*)d_in[1];
    const float* mask  = (const float*)d_in[2];
    float* out     = (float*)d_out;
    float* out_ind = out + (size_t)B_ * L_ * D_;
    uint32_t* keepw = (uint32_t*)d_ws;   // B_*L_/32 = 8192 words (32 KB)

    hipLaunchKernelGGL(select_kernel, dim3(B_), dim3(1024), 0, stream,
                       probs, mask, out_ind, keepw);
    const int n4 = (B_ * L_ * D_) / 4;   // 8,388,608 float4 elements
    hipLaunchKernelGGL(scatter_kernel, dim3(n4 / 256), dim3(256), 0, stream,
                       reps, keepw, out);
}